// Round 4
// baseline (302.839 us; speedup 1.0000x reference)
//
#include <hip/hip_runtime.h>
#include <hip/hip_bf16.h>

#define N_TOK 16384
#define DIM   2048
#define NEXP  64
#define BM    32            // tokens per block
#define KS    4             // K-split across the block's 4 waves
#define KW    (DIM / KS)    // 512 k per wave
#define CK    64            // k per staged chunk
#define NCH   (KW / CK)     // 8 chunks per wave
#define NBLK  (N_TOK / BM)  // 512

// d_out layout (all float32), reference tuple order:
// (l_aux, indices1_s[N], capacity, locations1_s[N], gates1_s[N], E)
#define OFF_LAUX  0
#define OFF_IDX   1
#define OFF_CAP   (1 + N_TOK)
#define OFF_LOC   (2 + N_TOK)
#define OFF_GATES (2 + 2 * N_TOK)
#define OFF_E     (2 + 3 * N_TOK)

typedef __attribute__((address_space(1))) const float gfloat;
typedef __attribute__((address_space(3))) float lfloat;

// ---------------------------------------------------------------------------
// Kernel 1: fp32 logits GEMM on the vector ALU, restructured per r3 counters:
//  - per-lane tile 8 tok x 4 exp; A from LDS with 16-lane BROADCAST reads
//    (4 distinct addrs/instr, XOR-swizzled across bank quads -> cheap on the
//    per-CU LDS pipe); B (wg, 512 KB, L2/L1-resident) per-lane from global.
//  - K-split x4: wave w owns k in [512w, 512w+512). 512 blocks x 4 waves =
//    2048 waves = 2/SIMD. Each wave double-buffers its PRIVATE 8 KB A chunk
//    via global_load_lds(16) + counted s_waitcnt vmcnt(8) -> no barriers in
//    the main loop.
//  - epilogue: cross-wave partial reduce in LDS, 8-lane-group shuffle
//    softmax/argmax (first-max tie-break), LDS-atomic me, ballot ranks.
// LDS: a_s 64 KB (+small) -> 2 blocks/CU. VGPR ~90.
//
// A staging map (hand-verified): instr j stages tokens 4j..4j+3; lane r*16+q
// (r=lane>>4, q=lane&15) writes dest floats [ (4j+r)*64 + 4q .. +3 ] = HW
// rule base+lane*16B. Source k-group is PRE-SWIZZLED: kq_src = q ^ tg(tok),
// tg(tok) = (tok>>3)&3, so read-side addr (8tg+m)*64 + 4*(kq^tg) lands the 4
// distinct tg-rows on 4 distinct bank quads (conflict-free) and XORs cancel.
// ---------------------------------------------------------------------------
__global__ __launch_bounds__(256)
void gate_gemm_kernel(const float* __restrict__ inp,
                      const float* __restrict__ wg,
                      float* __restrict__ out,
                      float* __restrict__ me_p,
                      int* __restrict__ hist,
                      int* __restrict__ idx_g,
                      int* __restrict__ rank_g)
{
    __shared__ float a_s[KS][2][BM * CK];   // 4 waves x 2 bufs x 8 KB = 64 KB
    __shared__ float me_s[NEXP];
    __shared__ int   am_s[BM];

    const int tid  = threadIdx.x;
    const int w    = tid >> 6;      // wave 0..3 -> k range
    const int lane = tid & 63;
    const int tg   = lane >> 4;     // token group 0..3 (8 tokens each)
    const int eg   = lane & 15;     // expert group 0..15 (4 experts each)
    const int blk  = blockIdx.x;
    const int row0 = blk * BM;

    const float4* wg4 = reinterpret_cast<const float4*>(wg);

    float acc[8][4];
    #pragma unroll
    for (int m = 0; m < 8; ++m)
        #pragma unroll
        for (int j = 0; j < 4; ++j) acc[m][j] = 0.f;

    // ---- stage one 32x64 A chunk into this wave's buffer bb (8 instrs) ----
    auto stage = [&](int bb, int c) {
        const int kbase = w * KW + c * CK;
        #pragma unroll
        for (int j = 0; j < 8; ++j) {
            const int tj  = 4 * j + (lane >> 4);       // token in block
            const int tgj = tj >> 3;                   // its swizzle key
            const float* src = inp + (size_t)(row0 + tj) * DIM
                               + kbase + 4 * ((lane & 15) ^ tgj);
            __builtin_amdgcn_global_load_lds((const gfloat*)src,
                (lfloat*)&a_s[w][bb][j * 256], 16, 0, 0);
        }
    };

    stage(0, 0);

    int buf = 0;
    for (int c = 0; c < NCH; ++c) {
        if (c < NCH - 1) {
            stage(buf ^ 1, c + 1);                       // 8 newest in flight
            asm volatile("s_waitcnt vmcnt(8)" ::: "memory");  // chunk c done
        } else {
            asm volatile("s_waitcnt vmcnt(0)" ::: "memory");
        }
        const float* ab = &a_s[w][buf][0];
        const int kg0 = (w * KW + c * CK) >> 2;          // float4 base for B
        #pragma unroll 4
        for (int kq = 0; kq < 16; ++kq) {
            float4 bv[4];
            #pragma unroll
            for (int j = 0; j < 4; ++j)
                bv[j] = wg4[(4 * eg + j) * (DIM / 4) + kg0 + kq];
            const int ak = 4 * (kq ^ tg);
            #pragma unroll
            for (int m = 0; m < 8; ++m) {
                float4 av = *reinterpret_cast<const float4*>(
                    &ab[(8 * tg + m) * CK + ak]);
                #pragma unroll
                for (int j = 0; j < 4; ++j)
                    acc[m][j] += av.x * bv[j].x + av.y * bv[j].y
                               + av.z * bv[j].z + av.w * bv[j].w;
            }
        }
        buf ^= 1;
    }

    __syncthreads();                       // all waves done with a_s
    if (tid < NEXP) me_s[tid] = 0.f;

    // spill K-partials: part[w][tok][e] overlaid on a_s (32 KB of 64)
    float* part = &a_s[0][0][0];
    #pragma unroll
    for (int m = 0; m < 8; ++m) {
        const int t = 8 * tg + m;
        float4 v = make_float4(acc[m][0], acc[m][1], acc[m][2], acc[m][3]);
        *reinterpret_cast<float4*>(&part[(w * BM + t) * NEXP + 4 * eg]) = v;
    }
    __syncthreads();

    // thread -> token tid>>3, experts (tid&7)*8..+7 ; sum 4 K-partials
    const int tok = tid >> 3;
    const int e0  = (tid & 7) * 8;
    float lgv[8];
    #pragma unroll
    for (int h = 0; h < 8; ++h) lgv[h] = 0.f;
    #pragma unroll
    for (int w2 = 0; w2 < KS; ++w2) {
        #pragma unroll
        for (int q = 0; q < 2; ++q) {
            float4 p = *reinterpret_cast<const float4*>(
                &part[(w2 * BM + tok) * NEXP + e0 + 4 * q]);
            lgv[4 * q + 0] += p.x; lgv[4 * q + 1] += p.y;
            lgv[4 * q + 2] += p.z; lgv[4 * q + 3] += p.w;
        }
    }

    // softmax/argmax across the 8-lane group owning this token
    float mx = lgv[0]; int ai = e0;
    #pragma unroll
    for (int h = 1; h < 8; ++h)
        if (lgv[h] > mx) { mx = lgv[h]; ai = e0 + h; }
    #pragma unroll
    for (int d = 1; d < 8; d <<= 1) {
        float om = __shfl_xor(mx, d);
        int   oi = __shfl_xor(ai, d);
        if (om > mx || (om == mx && oi < ai)) { mx = om; ai = oi; }  // first max
    }
    float pv[8], s = 0.f;
    #pragma unroll
    for (int h = 0; h < 8; ++h) { pv[h] = expf(lgv[h] - mx); s += pv[h]; }
    #pragma unroll
    for (int d = 1; d < 8; d <<= 1) s += __shfl_xor(s, d);
    const float inv = 1.0f / s;            // gate at argmax: exp(0)/s

    // per-expert me partial: sum over this wave's 8 tokens, then lanes 0..7
    float mep[8];
    #pragma unroll
    for (int h = 0; h < 8; ++h) mep[h] = pv[h] * inv;
    #pragma unroll
    for (int d = 8; d < 64; d <<= 1)
        #pragma unroll
        for (int h = 0; h < 8; ++h) mep[h] += __shfl_xor(mep[h], d);
    if (lane < 8) {
        #pragma unroll
        for (int h = 0; h < 8; ++h)
            atomicAdd(&me_s[lane * 8 + h], mep[h]);   // 4 waves contend only
    }

    if ((tid & 7) == 0) {
        am_s[tok] = ai;
        idx_g[row0 + tok] = ai;
        out[OFF_IDX + row0 + tok]   = (float)ai;
        out[OFF_GATES + row0 + tok] = inv;
    }
    __syncthreads();

    if (tid < NEXP) me_p[blk * NEXP + tid] = me_s[tid];

    // per-block histogram + in-block token-order rank via ballot (lanes 0..31)
    if (tid < BM) {
        const int am = am_s[tid];
        unsigned long long below = (1ull << tid) - 1ull;
        int rank = 0;
        for (int e = 0; e < NEXP; ++e) {
            unsigned long long bal = __ballot(am == e);
            if (am == e) rank = (int)__popcll(bal & below);
            if (tid == 0) hist[blk * NEXP + e] = (int)__popcll(bal);
        }
        rank_g[row0 + tid] = rank;
    }
}

// ---------------------------------------------------------------------------
// Kernel 2: per-expert exclusive scan of 512 block histograms + me reduction
// + l_aux. Single block, 1024 threads: thread (g=tid>>6, e=tid&63).
// ---------------------------------------------------------------------------
__global__ __launch_bounds__(1024)
void scan_kernel(const int* __restrict__ hist,
                 int* __restrict__ offs,
                 const float* __restrict__ me_p,
                 float* __restrict__ out)
{
    __shared__ int   part[16][NEXP];
    __shared__ float pme[16][NEXP];
    const int tid = threadIdx.x;
    const int e = tid & 63;
    const int g = tid >> 6;     // 0..15

    int ps = 0; float ms = 0.f;
    for (int i = 0; i < 32; ++i) {
        const int b = g * 32 + i;
        ps += hist[b * NEXP + e];
        ms += me_p[b * NEXP + e];
    }
    part[g][e] = ps;
    pme[g][e]  = ms;
    __syncthreads();

    if (tid < NEXP) {
        int run = 0; float me = 0.f;
        for (int gg = 0; gg < 16; ++gg) {
            const int v = part[gg][e];
            part[gg][e] = run;   // exclusive over groups
            run += v;
            me  += pme[gg][e];
        }
        // run == ce[e]
        float la = me * (float)run;
        #pragma unroll
        for (int o = 32; o > 0; o >>= 1)
            la += __shfl_down(la, o);
        if (tid == 0) {
            out[OFF_LAUX] = la * 2.384185791015625e-07f;  // 64 / 16384^2
            out[OFF_CAP]  = 256.0f;                       // ceil(N/E) * 1.0
            out[OFF_E]    = 64.0f;
        }
    }
    __syncthreads();

    int run2 = part[g][e];
    for (int i = 0; i < 32; ++i) {
        const int b = g * 32 + i;
        offs[b * NEXP + e] = run2;
        run2 += hist[b * NEXP + e];
    }
}

// ---------------------------------------------------------------------------
// Kernel 3: locations = in-block rank + scanned per-expert block offset
// ---------------------------------------------------------------------------
__global__ __launch_bounds__(256)
void loc_kernel(const int* __restrict__ idx_g,
                const int* __restrict__ rank_g,
                const int* __restrict__ offs,
                float* __restrict__ out)
{
    int t = blockIdx.x * 256 + threadIdx.x;
    int e = idx_g[t];
    int b = t >> 5;   // token / BM
    out[OFF_LOC + t] = (float)(rank_g[t] + offs[b * NEXP + e]);
}

extern "C" void kernel_launch(void* const* d_in, const int* in_sizes, int n_in,
                              void* d_out, int out_size, void* d_ws, size_t ws_size,
                              hipStream_t stream)
{
    const float* inp = (const float*)d_in[0];   // [16384, 2048]
    const float* wg  = (const float*)d_in[1];   // [64, 2048]
    float* out = (float*)d_out;

    // workspace: me_p[512*64] f32 | hist[512*64] i32 | offs[512*64] i32 |
    //            idx[16384] i32 | rank[16384] i32  (~0.5 MB; all fully
    //            written by the kernels each call -> no memset needed)
    float* me_p = (float*)d_ws;
    int* hist   = (int*)d_ws + NBLK * NEXP;
    int* offs   = hist + NBLK * NEXP;
    int* idx_g  = offs + NBLK * NEXP;
    int* rank_g = idx_g + N_TOK;

    hipLaunchKernelGGL(gate_gemm_kernel, dim3(NBLK), dim3(256), 0, stream,
                       inp, wg, out, me_p, hist, idx_g, rank_g);
    hipLaunchKernelGGL(scan_kernel, dim3(1), dim3(1024), 0, stream,
                       hist, offs, me_p, out);
    hipLaunchKernelGGL(loc_kernel, dim3(N_TOK / 256), dim3(256), 0, stream,
                       idx_g, rank_g, offs, out);
}

// Round 5
// 239.693 us; speedup vs baseline: 1.2634x; 1.2634x over previous
//
#include <hip/hip_runtime.h>
#include <hip/hip_bf16.h>

#define N_TOK 16384
#define DIM   2048
#define NEXP  64
#define BM    64                 // tokens per block (4 waves x 16)
#define NBLK  (N_TOK / BM)       // 256 blocks = 1 per CU
#define NKS   (DIM / 32)         // 64 MFMA k-steps

// d_out layout (all float32), reference tuple order:
// (l_aux, indices1_s[N], capacity, locations1_s[N], gates1_s[N], E)
#define OFF_LAUX  0
#define OFF_IDX   1
#define OFF_CAP   (1 + N_TOK)
#define OFF_LOC   (2 + N_TOK)
#define OFF_GATES (2 + 2 * N_TOK)
#define OFF_E     (2 + 3 * N_TOK)

typedef __attribute__((ext_vector_type(8))) short short8;   // 8 bf16 = 4 VGPR
typedef __attribute__((ext_vector_type(4))) float f32x4;

__device__ __forceinline__ short f2bf(float x) {
    __hip_bfloat16 b = __float2bfloat16(x);          // RNE
    return __builtin_bit_cast(short, b);
}
__device__ __forceinline__ float bf2f(short s) {
    __hip_bfloat16 b = __builtin_bit_cast(__hip_bfloat16, s);
    return __bfloat162float(b);
}

// ---------------------------------------------------------------------------
// K0: split wg (fp32 [64][2048]) into 3 bf16 arrays ALREADY in the
// mfma_f32_16x16x32_bf16 B-fragment order:  idx = (s*4+g)*64 + lane,
// expert = 16g + (lane&15), k = 32s + (lane>>4)*8 + j  (j=0..7 contiguous).
// w = w1 + w2 + w3 with exact residuals (Sterbenz subtractions in fp32).
// ---------------------------------------------------------------------------
__global__ __launch_bounds__(256)
void prep_w_kernel(const float* __restrict__ wg,
                   short8* __restrict__ w1a,
                   short8* __restrict__ w2a,
                   short8* __restrict__ w3a)
{
    const int id = blockIdx.x * 256 + threadIdx.x;   // 0..16383
    const int s = id >> 8;
    const int g = (id >> 6) & 3;
    const int l = id & 63;
    const int e  = 16 * g + (l & 15);
    const int k0 = 32 * s + (l >> 4) * 8;
    const float4* p = reinterpret_cast<const float4*>(wg + (size_t)e * DIM + k0);
    float4 v0 = p[0], v1 = p[1];
    float f[8] = {v0.x, v0.y, v0.z, v0.w, v1.x, v1.y, v1.z, v1.w};
    short8 b1, b2, b3;
    #pragma unroll
    for (int j = 0; j < 8; ++j) {
        b1[j] = f2bf(f[j]);
        float r = f[j] - bf2f(b1[j]);
        b2[j] = f2bf(r);
        float r2 = r - bf2f(b2[j]);
        b3[j] = f2bf(r2);
    }
    w1a[id] = b1; w2a[id] = b2; w3a[id] = b3;
}

// ---------------------------------------------------------------------------
// K1: logits via 6 bf16 MFMAs per 32-k step (fp32-exact 3-way split:
// a1w1 + a1w2 + a2w1 + a1w3 + a2w2 + a3w1; dropped terms O(2^-25)).
// A fragments load DIRECTLY global->VGPR in fragment order (lane: token
// row0+16w+(l&15), k=32s+(l>>4)*8; two dwordx4 = 16 x 64B segments/instr),
// 3-deep prefetch ring, no LDS / barriers in the main loop. B fragments
// stream from the pre-split L2-resident arrays (1 KB coalesced per load).
// Epilogue: quad-shuffle softmax/argmax (first-max), column-sum me,
// 64-lane ballot -> token-order ranks + per-block histogram.
// ---------------------------------------------------------------------------
__global__ __launch_bounds__(256)
void gate_mfma_kernel(const float* __restrict__ inp,
                      const short8* __restrict__ w1a,
                      const short8* __restrict__ w2a,
                      const short8* __restrict__ w3a,
                      float* __restrict__ out,
                      float* __restrict__ me_p,
                      int* __restrict__ hist,
                      int* __restrict__ idx_g,
                      int* __restrict__ rank_g)
{
    __shared__ float lg[BM][NEXP + 1];   // logits then P-values; +1 anti-conflict
    __shared__ float pme[4][NEXP];
    __shared__ int   am_s[BM];

    const int tid  = threadIdx.x;
    const int w    = tid >> 6;
    const int lane = tid & 63;
    const int blk  = blockIdx.x;
    const int row0 = blk * BM;

    const float* aptr = inp + (size_t)(row0 + 16 * w + (lane & 15)) * DIM
                        + ((lane >> 4) * 8);

    f32x4 acc[4] = {{0.f,0.f,0.f,0.f},{0.f,0.f,0.f,0.f},
                    {0.f,0.f,0.f,0.f},{0.f,0.f,0.f,0.f}};

    float4 af[4][2];                      // prefetch ring, slot = s&3
    #pragma unroll
    for (int s = 0; s < 3; ++s) {
        af[s][0] = *reinterpret_cast<const float4*>(aptr + 32 * s);
        af[s][1] = *reinterpret_cast<const float4*>(aptr + 32 * s + 4);
    }

    #pragma unroll 4
    for (int s = 0; s < NKS; ++s) {
        if (s < NKS - 3) {                // slot indices constant-fold (unroll 4)
            af[(s + 3) & 3][0] = *reinterpret_cast<const float4*>(aptr + 32 * (s + 3));
            af[(s + 3) & 3][1] = *reinterpret_cast<const float4*>(aptr + 32 * (s + 3) + 4);
        }
        const float4 v0 = af[s & 3][0], v1 = af[s & 3][1];
        float f[8] = {v0.x, v0.y, v0.z, v0.w, v1.x, v1.y, v1.z, v1.w};
        short8 a1, a2, a3;
        #pragma unroll
        for (int j = 0; j < 8; ++j) {
            a1[j] = f2bf(f[j]);
            float r = f[j] - bf2f(a1[j]);
            a2[j] = f2bf(r);
            float r2 = r - bf2f(a2[j]);
            a3[j] = f2bf(r2);
        }
        const int sb = s * 4 * 64 + lane;
        #pragma unroll
        for (int g = 0; g < 4; ++g) {
            short8 b1 = w1a[sb + g * 64];
            short8 b2 = w2a[sb + g * 64];
            short8 b3 = w3a[sb + g * 64];
            acc[g] = __builtin_amdgcn_mfma_f32_16x16x32_bf16(a1, b3, acc[g], 0, 0, 0);
            acc[g] = __builtin_amdgcn_mfma_f32_16x16x32_bf16(a2, b2, acc[g], 0, 0, 0);
            acc[g] = __builtin_amdgcn_mfma_f32_16x16x32_bf16(a3, b1, acc[g], 0, 0, 0);
            acc[g] = __builtin_amdgcn_mfma_f32_16x16x32_bf16(a1, b2, acc[g], 0, 0, 0);
            acc[g] = __builtin_amdgcn_mfma_f32_16x16x32_bf16(a2, b1, acc[g], 0, 0, 0);
            acc[g] = __builtin_amdgcn_mfma_f32_16x16x32_bf16(a1, b1, acc[g], 0, 0, 0);
        }
    }

    // D layout (m89-verified): col = lane&15 (expert), row = (lane>>4)*4 + r
    #pragma unroll
    for (int g = 0; g < 4; ++g)
        #pragma unroll
        for (int r = 0; r < 4; ++r)
            lg[16 * w + ((lane >> 4) << 2) + r][16 * g + (lane & 15)] = acc[g][r];
    __syncthreads();

    // per-token softmax/argmax: quad (4 threads) per token, 16 experts each
    const int tok = tid >> 2;
    const int q   = tid & 3;
    float v[16];
    #pragma unroll
    for (int i = 0; i < 16; ++i) v[i] = lg[tok][q * 16 + i];
    float mx = v[0]; int ai = q * 16;
    #pragma unroll
    for (int i = 1; i < 16; ++i)
        if (v[i] > mx) { mx = v[i]; ai = q * 16 + i; }   // strict > = first max
    #pragma unroll
    for (int d = 1; d < 4; d <<= 1) {
        float om = __shfl_xor(mx, d);
        int   oi = __shfl_xor(ai, d);
        if (om > mx || (om == mx && oi < ai)) { mx = om; ai = oi; }
    }
    float p[16], sum = 0.f;
    #pragma unroll
    for (int i = 0; i < 16; ++i) { p[i] = expf(v[i] - mx); sum += p[i]; }
    #pragma unroll
    for (int d = 1; d < 4; d <<= 1) sum += __shfl_xor(sum, d);
    const float inv = 1.0f / sum;                     // gate at argmax
    #pragma unroll
    for (int i = 0; i < 16; ++i) lg[tok][q * 16 + i] = p[i] * inv;
    if (q == 0) {
        am_s[tok] = ai;
        idx_g[row0 + tok] = ai;
        out[OFF_IDX + row0 + tok]   = (float)ai;
        out[OFF_GATES + row0 + tok] = inv;
    }
    __syncthreads();

    // me[e] partials: thread (g2=tid>>6, e=tid&63) sums 16 token rows
    {
        const int e = tid & 63, g2 = tid >> 6;
        float a = 0.f;
        #pragma unroll
        for (int t = 0; t < 16; ++t) a += lg[g2 * 16 + t][e];
        pme[g2][e] = a;
    }
    __syncthreads();
    if (tid < NEXP)
        me_p[blk * NEXP + tid] = pme[0][tid] + pme[1][tid] + pme[2][tid] + pme[3][tid];

    // ranks + histogram: wave 0, lane = token (64 lanes = 64 tokens)
    if (tid < BM) {
        const int am = am_s[tid];
        const unsigned long long below = (1ull << tid) - 1ull;
        int rank = 0, cnt = 0;
        for (int e = 0; e < NEXP; ++e) {
            unsigned long long bal = __ballot(am == e);
            if (am == e)  rank = (int)__popcll(bal & below);
            if (tid == e) cnt  = (int)__popcll(bal);
        }
        rank_g[row0 + tid]    = rank;
        hist[blk * NEXP + tid] = cnt;
    }
}

// ---------------------------------------------------------------------------
// K2: per-expert exclusive scan of 256 block histograms + me reduction +
// l_aux. Single block, 1024 threads: thread (g=tid>>6, e=tid&63) owns 16 blks.
// ---------------------------------------------------------------------------
__global__ __launch_bounds__(1024)
void scan_kernel(const int* __restrict__ hist,
                 int* __restrict__ offs,
                 const float* __restrict__ me_p,
                 float* __restrict__ out)
{
    __shared__ int   part[16][NEXP];
    __shared__ float pme2[16][NEXP];
    const int tid = threadIdx.x;
    const int e = tid & 63;
    const int g = tid >> 6;     // 0..15, 16 blocks each

    int ps = 0; float ms = 0.f;
    for (int i = 0; i < 16; ++i) {
        const int b = g * 16 + i;
        ps += hist[b * NEXP + e];
        ms += me_p[b * NEXP + e];
    }
    part[g][e] = ps;
    pme2[g][e] = ms;
    __syncthreads();

    if (tid < NEXP) {
        int run = 0; float me = 0.f;
        for (int gg = 0; gg < 16; ++gg) {
            const int v = part[gg][e];
            part[gg][e] = run;           // exclusive over groups
            run += v;
            me  += pme2[gg][e];
        }
        float la = me * (float)run;      // run == ce[e]
        #pragma unroll
        for (int o = 32; o > 0; o >>= 1)
            la += __shfl_down(la, o);
        if (tid == 0) {
            out[OFF_LAUX] = la * 2.384185791015625e-07f;  // 64 / 16384^2
            out[OFF_CAP]  = 256.0f;                        // ceil(N/E) * 1.0
            out[OFF_E]    = 64.0f;
        }
    }
    __syncthreads();

    int run2 = part[g][e];
    for (int i = 0; i < 16; ++i) {
        const int b = g * 16 + i;
        offs[b * NEXP + e] = run2;
        run2 += hist[b * NEXP + e];
    }
}

// ---------------------------------------------------------------------------
// K3: locations = in-block rank + scanned per-expert block offset
// ---------------------------------------------------------------------------
__global__ __launch_bounds__(256)
void loc_kernel(const int* __restrict__ idx_g,
                const int* __restrict__ rank_g,
                const int* __restrict__ offs,
                float* __restrict__ out)
{
    int t = blockIdx.x * 256 + threadIdx.x;
    int e = idx_g[t];
    int b = t >> 6;   // token / BM
    out[OFF_LOC + t] = (float)(rank_g[t] + offs[b * NEXP + e]);
}

extern "C" void kernel_launch(void* const* d_in, const int* in_sizes, int n_in,
                              void* d_out, int out_size, void* d_ws, size_t ws_size,
                              hipStream_t stream)
{
    const float* inp = (const float*)d_in[0];   // [16384, 2048]
    const float* wg  = (const float*)d_in[1];   // [64, 2048]
    float* out = (float*)d_out;

    // ws: w1a|w2a|w3a (3 x 256 KB bf16 frag arrays) | me_p 64KB | hist 64KB |
    //     offs 64KB | idx 64KB | rank 64KB   (~1.1 MB, fully rewritten per call)
    short8* w1a = (short8*)d_ws;
    short8* w2a = w1a + 16384;
    short8* w3a = w2a + 16384;
    float* me_p = (float*)(w3a + 16384);
    int* hist   = (int*)(me_p + NBLK * NEXP);
    int* offs   = hist + NBLK * NEXP;
    int* idx_g  = offs + NBLK * NEXP;
    int* rank_g = idx_g + N_TOK;

    hipLaunchKernelGGL(prep_w_kernel, dim3(64), dim3(256), 0, stream,
                       wg, w1a, w2a, w3a);
    hipLaunchKernelGGL(gate_mfma_kernel, dim3(NBLK), dim3(256), 0, stream,
                       inp, w1a, w2a, w3a, out, me_p, hist, idx_g, rank_g);
    hipLaunchKernelGGL(scan_kernel, dim3(1), dim3(1024), 0, stream,
                       hist, offs, me_p, out);
    hipLaunchKernelGGL(loc_kernel, dim3(N_TOK / 256), dim3(256), 0, stream,
                       idx_g, rank_g, offs, out);
}